// Round 4
// baseline (433.769 us; speedup 1.0000x reference)
//
#include <hip/hip_runtime.h>
#include <hip/hip_bf16.h>

// SDNN: xw1 = x@w1[:, :1024]+b1 ; h[:,j]=relu(xw1[:,j]+h@w2[:,j]) j<1024 ;
//       out = h@w3[:1024]+x@w4+b2.
// R3->R4 (recurrence is DS-pipe-bound, not latency-bound):
//   - triangular exec-masking: lanes with g<jg skip w2blk reads/bperms/updates
//   - owner-only chain compute (frees VALU issue slots)
//   - aq LDS reads hoisted out of the f-loop (address is f-independent)
//   - w2blk double-buffered; next block's global_load_lds issued before the
//     solve so it completes under it (T14) instead of stalling at the barrier.

typedef __bf16 bf16x8 __attribute__((ext_vector_type(8)));
typedef float f32x4 __attribute__((ext_vector_type(4)));
typedef int i32x4 __attribute__((ext_vector_type(4)));

__device__ __forceinline__ void gload_lds16(const void* gsrc, void* ldst) {
#if __has_builtin(__builtin_amdgcn_global_load_lds)
  void* g = const_cast<void*>(gsrc);
  __builtin_amdgcn_global_load_lds((__attribute__((address_space(1))) void*)g,
                                   (__attribute__((address_space(3))) void*)ldst,
                                   16, 0, 0);
#else
  *(i32x4*)ldst = *(const i32x4*)gsrc;
#endif
}

// ---------- converts ----------
__global__ __launch_bounds__(256) void cvt_bf16x8(const float* __restrict__ src,
                                                  __hip_bfloat16* __restrict__ dst,
                                                  long n) {
  long i = ((long)blockIdx.x * blockDim.x + threadIdx.x) * 8;
  if (i >= n) return;
  f32x4 a = *(const f32x4*)(src + i);
  f32x4 b = *(const f32x4*)(src + i + 4);
  union { __hip_bfloat16 h[8]; i32x4 v; } u;
#pragma unroll
  for (int j = 0; j < 4; ++j) {
    u.h[j]     = __float2bfloat16(a[j]);
    u.h[4 + j] = __float2bfloat16(b[j]);
  }
  *(i32x4*)(dst + i) = u.v;
}

// dst[j][k] = (j < Juse) ? bf16(src[k][j]) : 0 ; dst is [1024][Kuse]
__global__ __launch_bounds__(256) void transpose_cvt(const float* __restrict__ src,
                                                     __hip_bfloat16* __restrict__ dst,
                                                     int srcStride, int Kuse, int Juse) {
  __shared__ float tile[32][33];
  const int k0 = blockIdx.x * 32, j0 = blockIdx.y * 32;
  const int tx = threadIdx.x, ty = threadIdx.y;  // 32 x 8
#pragma unroll
  for (int i = 0; i < 4; ++i) {
    const int k = k0 + ty + i * 8, j = j0 + tx;
    tile[ty + i * 8][tx] = (j < Juse) ? src[(size_t)k * srcStride + j] : 0.f;
  }
  __syncthreads();
#pragma unroll
  for (int i = 0; i < 4; ++i) {
    const int j = j0 + ty + i * 8, k = k0 + tx;
    dst[(size_t)j * Kuse + k] = __float2bfloat16(tile[tx][ty + i * 8]);
  }
}

// ---------- bf16 MFMA GEMM, C = sum_p A_p @ B_p^T + bias (m97 structure) ----------
template <int NP>
__global__ __launch_bounds__(256) void gemm_bf16_nt(
    const __hip_bfloat16* __restrict__ A0, const __hip_bfloat16* __restrict__ B0t, int K0,
    const __hip_bfloat16* __restrict__ A1, const __hip_bfloat16* __restrict__ B1t, int K1,
    const float* __restrict__ bias, float* __restrict__ C, int Cstride, int Nvalid) {
  __shared__ __align__(16) __hip_bfloat16 As[128 * 64];
  __shared__ __align__(16) __hip_bfloat16 Bs[128 * 64];
  const int tid = threadIdx.x;
  const int l = tid & 63;
  const int w = tid >> 6;
  const int wr = w >> 1, wc = w & 1;
  const int bm = blockIdx.x * 128;
  const int bn = blockIdx.y * 128;

  f32x4 acc[4][4] = {};

#pragma unroll
  for (int p = 0; p < NP; ++p) {
    const __hip_bfloat16* A  = (p == 0) ? A0 : A1;
    const __hip_bfloat16* Bt = (p == 0) ? B0t : B1t;
    const int K = (p == 0) ? K0 : K1;
    for (int kt = 0; kt < K; kt += 64) {
      __syncthreads();
      const int srow = tid >> 3;
      const int sk = (tid & 7) * 8;
#pragma unroll
      for (int i = 0; i < 4; ++i) {
        gload_lds16(A  + (size_t)(bm + i * 32 + srow) * K + kt + sk,
                    &As[(i * 32 + srow) * 64 + sk]);
        gload_lds16(Bt + (size_t)(bn + i * 32 + srow) * K + kt + sk,
                    &Bs[(i * 32 + srow) * 64 + sk]);
      }
      __syncthreads();
#pragma unroll
      for (int kk = 0; kk < 64; kk += 32) {
        const int ko = kk + (l >> 4) * 8;
        bf16x8 aq[4], bq[4];
#pragma unroll
        for (int m = 0; m < 4; ++m)
          aq[m] = *(const bf16x8*)&As[(wr * 64 + m * 16 + (l & 15)) * 64 + ko];
#pragma unroll
        for (int n = 0; n < 4; ++n)
          bq[n] = *(const bf16x8*)&Bs[(wc * 64 + n * 16 + (l & 15)) * 64 + ko];
#pragma unroll
        for (int m = 0; m < 4; ++m)
#pragma unroll
          for (int n = 0; n < 4; ++n)
            acc[m][n] = __builtin_amdgcn_mfma_f32_16x16x32_bf16(aq[m], bq[n], acc[m][n], 0, 0, 0);
      }
    }
  }
#pragma unroll
  for (int m = 0; m < 4; ++m) {
    const int row0 = bm + wr * 64 + m * 16 + (l >> 4) * 4;
#pragma unroll
    for (int n = 0; n < 4; ++n) {
      const int col = bn + wc * 64 + n * 16 + (l & 15);
      if (col < Nvalid) {
        const float bv = bias[col];
#pragma unroll
        for (int j = 0; j < 4; ++j)
          C[(size_t)(row0 + j) * Cstride + col] = acc[m][n][j] + bv;
      }
    }
  }
}

// ---------- recurrence (v4: masked solve, dbuf staging, hoisted aq) ----------
// Per WG: 16 rows, 16 blocks of 64 cols, grid=512 (2 WG/CU).
// Acc panel in registers: wave w, frag f covers cols (f*4+w)*16+fr, rows q*4+j.
// H LDS layout (bf16): elem (r,k) at r*1024 + (((k>>3)^(r&7))<<3) + (k&7)
__global__ __launch_bounds__(256) void recurrence_k(
    const float* __restrict__ xw1,            // [8192][1024]
    const float* __restrict__ w2,             // [2048][2048] f32
    const __hip_bfloat16* __restrict__ w2t,   // [1024][1024] bf16, [j][k] = w2[k][j]
    __hip_bfloat16* __restrict__ hidden) {    // [8192][1024]
  __shared__ __align__(16) __hip_bfloat16 H[16 * 1024];   // 32 KiB
  __shared__ __align__(16) float accS[16 * 68];           // [r][c], pad 68
  __shared__ __align__(16) float w2blk[2][64 * 64];       // dbuf, 2 x 16 KiB
  const int tid = threadIdx.x;
  const int l = tid & 63;
  const int w = tid >> 6;
  const int R0 = blockIdx.x * 16;
  const int rT = tid >> 4;  // solve row (0..15)
  const int g  = tid & 15;  // solve col group (4 cols each)
  const int q  = l >> 4;    // frag row-quarter
  const int fr = l & 15;    // frag col within 16

  // init acc panel from xw1 (frag layout: row=q*4+j, col=fr)
  f32x4 af[16];
#pragma unroll
  for (int f = 0; f < 16; ++f) {
    const int c = (f * 4 + w) * 16 + fr;
#pragma unroll
    for (int j = 0; j < 4; ++j)
      af[f][j] = xw1[(size_t)(R0 + q * 4 + j) * 1024 + c];
  }

  // stage w2 [64][64] f32 block at global col/row base B0s into w2blk[buf]
  auto stage = [&](int buf, int B0s) {
#pragma unroll
    for (int i = 0; i < 4; ++i) {
      const int e = i * 1024 + tid * 4;
      const int jj = e >> 6, c = e & 63;
      gload_lds16(w2 + (size_t)(B0s + jj) * 2048 + (B0s + c), &w2blk[buf][e]);
    }
  };

  stage(0, 0);  // prologue: block 0
  int cur = 0;

#pragma unroll 1
  for (int b = 0; b < 16; ++b) {
    const int B0 = b * 64;
    // (A) extract frag b -> accS[r][c]
#pragma unroll
    for (int f = 0; f < 16; ++f)
      if (f == b) {
#pragma unroll
        for (int j = 0; j < 4; ++j)
          accS[(q * 4 + j) * 68 + w * 16 + fr] = af[f][j];
      }
    __syncthreads();  // accS visible; w2blk[cur] staged (barrier drains vmcnt)
    // (B) issue next block's staging now; completes under the solve
    if (b < 15) stage(cur ^ 1, B0 + 64);
    // (C) in-block solve, triangular-masked. Thread: row rT, cols g*4..g*4+3.
    f32x4 ac = *(const f32x4*)&accS[rT * 68 + g * 4];
    const float* wb = w2blk[cur];
#pragma unroll
    for (int jg = 0; jg < 16; ++jg) {
      float h0 = 0.f, h1 = 0.f, h2 = 0.f, h3 = 0.f;
      if (g >= jg) {  // lanes with g<jg are done: no reads, no bperms, no VALU
        const int j0 = jg * 4;
        const f32x4 wr0 = *(const f32x4*)&wb[(j0 + 0) * 64 + g * 4];
        const f32x4 wr1 = *(const f32x4*)&wb[(j0 + 1) * 64 + g * 4];
        const f32x4 wr2 = *(const f32x4*)&wb[(j0 + 2) * 64 + g * 4];
        const f32x4 wr3 = *(const f32x4*)&wb[(j0 + 3) * 64 + g * 4];
        if (g == jg) {  // owner-only chain
          h0 = fmaxf(ac[0], 0.f);
          h1 = fmaxf(ac[1] + h0 * wr0[1], 0.f);
          h2 = fmaxf(ac[2] + h0 * wr0[2] + h1 * wr1[2], 0.f);
          h3 = fmaxf(ac[3] + h0 * wr0[3] + h1 * wr1[3] + h2 * wr2[3], 0.f);
        }
        const int src = (l & 48) | jg;
        const float b0 = __shfl(h0, src, 64);
        const float b1 = __shfl(h1, src, 64);
        const float b2 = __shfl(h2, src, 64);
        const float b3 = __shfl(h3, src, 64);
        if (g == jg) {
          const int k = B0 + j0;
          union { __hip_bfloat16 hh[4]; uint2 v; } u;
          u.hh[0] = __float2bfloat16(h0); u.hh[1] = __float2bfloat16(h1);
          u.hh[2] = __float2bfloat16(h2); u.hh[3] = __float2bfloat16(h3);
          *(uint2*)&H[rT * 1024 + (((k >> 3) ^ (rT & 7)) << 3) + (k & 7)] = u.v;
        } else {
#pragma unroll
          for (int i = 0; i < 4; ++i)
            ac[i] += b0 * wr0[i] + b1 * wr1[i] + b2 * wr2[i] + b3 * wr3[i];
        }
      }
    }
    __syncthreads();  // (D) H block visible to all
    // (E) copy this block's H to global hidden (16B per thread, 128 threads)
    if (tid < 128) {
      const int r5 = tid >> 3, seg = tid & 7;
      const int kk = B0 + seg * 8;
      const int gsw = (kk >> 3) ^ (r5 & 7);
      const i32x4 v = *(const i32x4*)&H[r5 * 1024 + gsw * 8];
      *(i32x4*)&hidden[(size_t)(R0 + r5) * 1024 + kk] = v;
    }
    // (F) right-looking update: frags f>b get H_blk @ w2t. aq is f-independent
    //     -> hoist (2 LDS reads per wave-block instead of 2 per frag).
    if (b < 15) {
      const int kr0 = B0 + q * 8;
      const int kr1 = B0 + 32 + q * 8;
      const bf16x8 aq0 = *(const bf16x8*)&H[fr * 1024 + (((kr0 >> 3) ^ (fr & 7)) << 3)];
      const bf16x8 aq1 = *(const bf16x8*)&H[fr * 1024 + (((kr1 >> 3) ^ (fr & 7)) << 3)];
#pragma unroll
      for (int f = 0; f < 16; ++f)
        if (f > b) {
          const int c = (f * 4 + w) * 16 + fr;
          const bf16x8 bq0 = *(const bf16x8*)&w2t[(size_t)c * 1024 + kr0];
          const bf16x8 bq1 = *(const bf16x8*)&w2t[(size_t)c * 1024 + kr1];
          af[f] = __builtin_amdgcn_mfma_f32_16x16x32_bf16(aq0, bq0, af[f], 0, 0, 0);
          af[f] = __builtin_amdgcn_mfma_f32_16x16x32_bf16(aq1, bq1, af[f], 0, 0, 0);
        }
    }
    cur ^= 1;
  }
}

extern "C" void kernel_launch(void* const* d_in, const int* in_sizes, int n_in,
                              void* d_out, int out_size, void* d_ws, size_t ws_size,
                              hipStream_t stream) {
  const float* x  = (const float*)d_in[0];
  const float* w1 = (const float*)d_in[1];
  const float* w2 = (const float*)d_in[2];
  const float* w3 = (const float*)d_in[3];
  const float* w4 = (const float*)d_in[4];
  const float* b1 = (const float*)d_in[5];
  const float* b2 = (const float*)d_in[6];
  float* out = (float*)d_out;

  char* ws = (char*)d_ws;
  size_t off = 0;
  auto alloc = [&](size_t bytes) {
    char* p = ws + off;
    off += (bytes + 255) & ~(size_t)255;
    return p;
  };
  __hip_bfloat16* x_bf = (__hip_bfloat16*)alloc(8192ull * 2048 * 2);
  float*          xw1  = (float*)alloc(8192ull * 1024 * 4);
  __hip_bfloat16* hid  = (__hip_bfloat16*)alloc(8192ull * 1024 * 2);
  __hip_bfloat16* w1t  = (__hip_bfloat16*)alloc(1024ull * 2048 * 2);
  __hip_bfloat16* w2t  = (__hip_bfloat16*)alloc(1024ull * 1024 * 2);
  __hip_bfloat16* w3t  = (__hip_bfloat16*)alloc(1024ull * 1024 * 2);
  __hip_bfloat16* w4t  = (__hip_bfloat16*)alloc(1024ull * 2048 * 2);

  cvt_bf16x8<<<dim3(8192), dim3(256), 0, stream>>>(x, x_bf, 8192L * 2048);

  dim3 tb(32, 8);
  transpose_cvt<<<dim3(64, 32), tb, 0, stream>>>(w1, w1t, 2048, 2048, 1024);
  transpose_cvt<<<dim3(32, 32), tb, 0, stream>>>(w2, w2t, 2048, 1024, 1024);
  transpose_cvt<<<dim3(32, 32), tb, 0, stream>>>(w3, w3t, 1000, 1024, 1000);
  transpose_cvt<<<dim3(64, 32), tb, 0, stream>>>(w4, w4t, 1000, 2048, 1000);

  // xw1 = x @ w1[:, :1024] + b1
  gemm_bf16_nt<1><<<dim3(64, 8), dim3(256), 0, stream>>>(
      x_bf, w1t, 2048, (const __hip_bfloat16*)nullptr, (const __hip_bfloat16*)nullptr, 0,
      b1, xw1, 1024, 1024);

  recurrence_k<<<dim3(512), dim3(256), 0, stream>>>(xw1, w2, w2t, hid);

  // out = hidden @ w3[:1024] + x @ w4 + b2
  gemm_bf16_nt<2><<<dim3(64, 8), dim3(256), 0, stream>>>(
      hid, w3t, 1024, x_bf, w4t, 2048, b2, out, 1000, 1000);

  (void)in_sizes; (void)n_in; (void)out_size; (void)ws_size;
}